// Round 6
// baseline (156.416 us; speedup 1.0000x reference)
//
#include <hip/hip_runtime.h>
#include <hip/hip_bf16.h>
#include <stdint.h>

#define NN 100000
#define EE 1600000
#define CAP 128           // srclist slots per dst (max unique in-degree ~70)
#define NB 782            // ceil(NN/128) dst buckets
#define CAPB 5120         // bucket capacity (mean ~4092, sigma ~64)
#define HTS 8192          // per-bucket LDS hash slots
#define EMPTY 0xFFFFFFFFu
#define BIN_CHUNK 2048    // input edge pairs per bin block
#define GL 782            // linear block count: ceil(NN/128)
#define GB 782            // bin block count: ceil(EE/BIN_CHUNK)

__device__ __forceinline__ unsigned int mix32(unsigned int x){
  x ^= x >> 16; x *= 0x7feb352du;
  x ^= x >> 15; x *= 0x846ca68bu;
  x ^= x >> 16;
  return x;
}

// Fused: odd blocks bin edges, even blocks compute h = bf16(x @ W^T + b).
// Parity interleave keeps a linear:bin mix resident on every CU for the whole
// dispatch, hiding bin's LDS-atomic latency under linear's FMA throughput.
extern "C" __global__ __launch_bounds__(256)
void k_prep(const float* __restrict__ x, const float* __restrict__ W,
            const float* __restrict__ bias, __hip_bfloat16* __restrict__ hb,
            const int* __restrict__ ei, int* __restrict__ bcnt,
            unsigned int* __restrict__ bbuf){
  __shared__ __align__(16) char sm[51200];
  const int tid = threadIdx.x;

  if (!(blockIdx.x & 1)){
    // ---------------- linear path (even blocks) ----------------
    const int lb = blockIdx.x >> 1;
    float (*wt)[64] = reinterpret_cast<float(*)[64]>(sm);            // 16 KB
    float (*xs)[68] = reinterpret_cast<float(*)[68]>(sm + 16384);    // 34.8 KB
    const int lane = tid & 63;
    const int w    = tid >> 6;
    #pragma unroll
    for (int r = 0; r < 16; ++r){
      int i = r*4 + w;
      wt[i][lane] = W[lane*64 + i];
    }
    const int nbase = lb * 128;
    #pragma unroll
    for (int r = 0; r < 8; ++r){
      int idx = r*256 + tid;
      int nl  = idx >> 4;
      int c4  = idx & 15;
      int n   = nbase + nl;
      float4 v = make_float4(0.f,0.f,0.f,0.f);
      if (n < NN) v = reinterpret_cast<const float4*>(x)[(size_t)n*16 + c4];
      *reinterpret_cast<float4*>(&xs[nl][c4*4]) = v;
    }
    __syncthreads();

    const int og  = tid & 7;
    const int nl0 = (tid >> 3) * 4;
    float acc[4][8];
    #pragma unroll
    for (int t=0;t<4;++t){
      #pragma unroll
      for (int j=0;j<8;++j) acc[t][j]=0.f;
    }
    #pragma unroll 4
    for (int i=0;i<64;++i){
      float4 wa = *reinterpret_cast<const float4*>(&wt[i][og*8]);
      float4 wb = *reinterpret_cast<const float4*>(&wt[i][og*8+4]);
      #pragma unroll
      for (int t=0;t<4;++t){
        float xv = xs[nl0+t][i];
        acc[t][0] += xv*wa.x; acc[t][1] += xv*wa.y;
        acc[t][2] += xv*wa.z; acc[t][3] += xv*wa.w;
        acc[t][4] += xv*wb.x; acc[t][5] += xv*wb.y;
        acc[t][6] += xv*wb.z; acc[t][7] += xv*wb.w;
      }
    }
    float4 b0 = reinterpret_cast<const float4*>(bias)[og*2];
    float4 b1 = reinterpret_cast<const float4*>(bias)[og*2+1];
    float bb[8] = {b0.x,b0.y,b0.z,b0.w,b1.x,b1.y,b1.z,b1.w};
    #pragma unroll
    for (int t=0;t<4;++t){
      int n = nbase + nl0 + t;
      if (n < NN){
        union { uint4 u4; __hip_bfloat16 v[8]; } pk;
        #pragma unroll
        for (int j=0;j<8;++j) pk.v[j] = __float2bfloat16(acc[t][j] + bb[j]);
        reinterpret_cast<uint4*>(&hb[(size_t)n*64])[og] = pk.u4;
      }
    }
  } else {
    // ---------------- bin path (odd blocks) ----------------
    const int bb_id = blockIdx.x >> 1;
    int* hist  = reinterpret_cast<int*>(sm);
    int* bbase = hist + NB;
    int* bcur  = bbase + NB;
    for (int i = tid; i < NB; i += 256) hist[i] = 0;
    __syncthreads();
    const int e0 = bb_id * BIN_CHUNK;
    #pragma unroll 1
    for (int r = 0; r < BIN_CHUNK; r += 256){
      int i = e0 + r + tid;
      if (i < EE){
        int a = ei[i], c = ei[EE + i];
        atomicAdd(&hist[c >> 7], 1);
        atomicAdd(&hist[a >> 7], 1);
      }
    }
    __syncthreads();
    for (int bk = tid; bk < NB; bk += 256){
      int hh = hist[bk];
      bbase[bk] = hh ? atomicAdd(&bcnt[bk], hh) : 0;
      bcur[bk]  = 0;
    }
    __syncthreads();
    #pragma unroll 1
    for (int r = 0; r < BIN_CHUNK; r += 256){
      int i = e0 + r + tid;
      if (i < EE){
        int a = ei[i], c = ei[EE + i];
        int b1 = c >> 7, b2 = a >> 7;
        int p1 = bbase[b1] + atomicAdd(&bcur[b1], 1);
        int p2 = bbase[b2] + atomicAdd(&bcur[b2], 1);
        if (p1 < CAPB) bbuf[(size_t)b1*CAPB + p1] = ((unsigned)a << 7) | (unsigned)(c & 127);
        if (p2 < CAPB) bbuf[(size_t)b2*CAPB + p2] = ((unsigned)c << 7) | (unsigned)(a & 127);
      }
    }
  }
}

// One block per bucket: dedup in LDS hash, inject self loops, then a single
// HT scan that simultaneously compacts src lists and counts degrees.
extern "C" __global__ __launch_bounds__(256)
void k_dedup(const int* __restrict__ bcnt, const unsigned int* __restrict__ bbuf,
             unsigned int* __restrict__ srclist, int* __restrict__ cnt,
             float* __restrict__ inv){
  __shared__ unsigned int HT[HTS];   // 32KB
  __shared__ int dcur[128];
  const int tid = threadIdx.x;
  const int b   = blockIdx.x;
  const int d0  = b << 7;
  for (int i = tid; i < HTS; i += 256) HT[i] = EMPTY;
  if (tid < 128) dcur[tid] = 0;
  __syncthreads();

  int n = bcnt[b]; if (n > CAPB) n = CAPB;
  const unsigned int* buf = bbuf + (size_t)b * CAPB;
  for (int k = tid; k < n; k += 256){
    unsigned int pk  = buf[k];
    unsigned int idx = mix32(pk) & (HTS-1);
    for (;;){
      unsigned int prev = atomicCAS(&HT[idx], EMPTY, pk);
      if (prev == EMPTY || prev == pk) break;
      idx = (idx + 1) & (HTS-1);
    }
  }
  if (tid < 128 && d0 + tid < NN){      // self loop (src=dst=d0+tid)
    unsigned int pk  = ((unsigned)(d0 + tid) << 7) | (unsigned)tid;
    unsigned int idx = mix32(pk) & (HTS-1);
    for (;;){
      unsigned int prev = atomicCAS(&HT[idx], EMPTY, pk);
      if (prev == EMPTY || prev == pk) break;
      idx = (idx + 1) & (HTS-1);
    }
  }
  __syncthreads();

  // single scan: compact + count
  for (int i = tid; i < HTS; i += 256){
    unsigned int v = HT[i];
    if (v != EMPTY){
      int dl  = v & 127;
      int pos = atomicAdd(&dcur[dl], 1);
      if (pos < CAP) srclist[(size_t)(d0 + dl) * CAP + pos] = v >> 7;
    }
  }
  __syncthreads();
  if (tid < 128 && d0 + tid < NN){
    int c = dcur[tid];
    cnt[d0 + tid] = c;
    inv[d0 + tid] = rsqrtf((float)c);
  }
}

// One wave per dst. lane = dim-PAIR (u32 = 2 bf16); half-wave 0 processes
// even edges, half-wave 1 odd edges; 8 pair-accumulators (8 gathers in
// flight per wave); __shfl_xor(32) combine; float2 coalesced store.
extern "C" __global__ __launch_bounds__(256)
void k_agg(const __hip_bfloat16* __restrict__ hb, const float* __restrict__ inv,
           const int* __restrict__ cnt, const unsigned int* __restrict__ srclist,
           float* __restrict__ out){
  __shared__ uint2 sv[4][CAP];   // .x = src, .y = f32 bits of inv[src]
  const int wv   = threadIdx.x >> 6;
  const int lane = threadIdx.x & 63;
  const int half = lane >> 5;
  const int pl   = lane & 31;
  const int d    = blockIdx.x*4 + wv;
  if (d >= NN) return;
  const unsigned int* reg = srclist + (size_t)d * CAP;
  int c = cnt[d]; if (c > CAP) c = CAP;
  const int c16 = (c + 15) & ~15;

  if (lane < c){
    unsigned s = reg[lane];
    sv[wv][lane] = make_uint2(s, __float_as_uint(inv[s]));
  }
  if (64 + lane < c){
    unsigned s = reg[64 + lane];
    sv[wv][64 + lane] = make_uint2(s, __float_as_uint(inv[s]));
  }
  { int p = c + lane; if (p < c16) sv[wv][p] = make_uint2(0u, 0u); }

  const char* hbase = (const char*)hb;
  const int   boff  = pl << 2;    // byte offset of this dim pair within a row
  float ax[8], ay[8];
  #pragma unroll
  for (int u=0;u<8;++u){ ax[u]=0.f; ay[u]=0.f; }
  #pragma unroll 1
  for (int j = 0; j < c16; j += 16){
    #pragma unroll
    for (int u = 0; u < 8; ++u){
      uint2 e = sv[wv][j + 2*u + half];
      float w = __uint_as_float(e.y);
      unsigned hv = *reinterpret_cast<const unsigned*>(hbase + ((size_t)e.x << 7) + boff);
      ax[u] += w * __uint_as_float(hv << 16);
      ay[u] += w * __uint_as_float(hv & 0xFFFF0000u);
    }
  }
  float rx = ((ax[0]+ax[1])+(ax[2]+ax[3])) + ((ax[4]+ax[5])+(ax[6]+ax[7]));
  float ry = ((ay[0]+ay[1])+(ay[2]+ay[3])) + ((ay[4]+ay[5])+(ay[6]+ay[7]));
  rx += __shfl_xor(rx, 32);
  ry += __shfl_xor(ry, 32);
  if (half == 0){
    float iv = inv[d];
    float2 o = make_float2(rx * iv, ry * iv);
    *reinterpret_cast<float2*>(&out[(size_t)d*64 + (pl << 1)]) = o;
  }
}

extern "C" void kernel_launch(void* const* d_in, const int* in_sizes, int n_in,
                              void* d_out, int out_size, void* d_ws, size_t ws_size,
                              hipStream_t stream){
  (void)in_sizes; (void)n_in; (void)out_size; (void)ws_size;
  const float* x  = (const float*)d_in[0];
  const int*   ei = (const int*)  d_in[1];
  const float* W  = (const float*)d_in[2];
  const float* b  = (const float*)d_in[3];
  float* out = (float*)d_out;

  char* ws = (char*)d_ws;
  __hip_bfloat16* hb      = (__hip_bfloat16*)ws;            // 12.8 MB
  float*          inv     = (float*)(ws + 12800000);        // 0.4 MB
  int*            cnt     = (int*)  (ws + 13200000);        // 0.4 MB
  unsigned int*   srclist = (unsigned int*)(ws + 13600000); // 51.2 MB
  int*            bcnt    = (int*)  (ws + 64800000);        // 4 KB
  unsigned int*   bbuf    = (unsigned int*)(ws + 64804096); // 16.0 MB (end ~80.8 MB)

  hipMemsetAsync(bcnt, 0, NB * 4, stream);

  k_prep  <<<GL + GB, 256, 0, stream>>>(x, W, b, hb, ei, bcnt, bbuf);
  k_dedup <<<NB, 256, 0, stream>>>(bcnt, bbuf, srclist, cnt, inv);
  k_agg   <<<(NN + 3)/4, 256, 0, stream>>>(hb, inv, cnt, srclist, out);
}

// Round 7
// 142.181 us; speedup vs baseline: 1.1001x; 1.1001x over previous
//
#include <hip/hip_runtime.h>
#include <hip/hip_bf16.h>
#include <stdint.h>

#define NN 100000
#define EE 1600000
#define CAP 128           // srclist slots per dst (max unique in-degree ~70)
#define NB 782            // ceil(NN/128) dst buckets
#define CAPB 5120         // bucket capacity (mean ~4092, sigma ~64)
#define HTS 8192          // per-bucket LDS hash slots
#define EMPTY 0xFFFFFFFFu
#define GLIN 1563         // linear blocks: ceil(NN/64)
#define GBIN 391          // bin blocks: ceil(EE/4096)

__device__ __forceinline__ unsigned int mix32(unsigned int x){
  x ^= x >> 16; x *= 0x7feb352du;
  x ^= x >> 15; x *= 0x846ca68bu;
  x ^= x >> 16;
  return x;
}

// Fused linear+bin. LDS capped at 25KB -> 6 blocks/CU (was 51.2KB -> 3).
// 4:1 interleave keeps both block species resident on every CU.
extern "C" __global__ __launch_bounds__(256)
void k_prep(const float* __restrict__ x, const float* __restrict__ W,
            const float* __restrict__ bias, __hip_bfloat16* __restrict__ hb,
            const int* __restrict__ ei, int* __restrict__ bcnt,
            unsigned int* __restrict__ bbuf){
  __shared__ __align__(16) char sm[25088];
  const int tid = threadIdx.x;
  const int bid = blockIdx.x;
  bool isbin; int sub;
  if (bid < 1950){ isbin = ((bid % 5) == 4); sub = isbin ? (bid/5) : (bid - bid/5); }
  else if (bid < 1953){ isbin = false; sub = bid - 390; }
  else { isbin = true; sub = 390; }

  if (!isbin){
    // ---------- linear: 64 nodes/block, x staged bf16-transposed ----------
    float (*wt)[64]           = reinterpret_cast<float(*)[64]>(sm);            // 16KB  wt[i][o]=W[o][i]
    __hip_bfloat16 (*xs)[68]  = reinterpret_cast<__hip_bfloat16(*)[68]>(sm + 16384); // 8.7KB xs[i][n]
    const int lane = tid & 63;
    const int wv   = tid >> 6;
    #pragma unroll
    for (int r = 0; r < 16; ++r){
      int i = r*4 + wv;
      wt[i][lane] = W[lane*64 + i];
    }
    const int nbase = sub * 64;
    #pragma unroll
    for (int r = 0; r < 4; ++r){
      int idx = r*256 + tid;          // float4 slot in [64][16]
      int nl  = idx >> 4;
      int c4  = idx & 15;
      int n   = nbase + nl;
      float4 v = make_float4(0.f,0.f,0.f,0.f);
      if (n < NN) v = reinterpret_cast<const float4*>(x)[(size_t)n*16 + c4];
      xs[c4*4+0][nl] = __float2bfloat16(v.x);
      xs[c4*4+1][nl] = __float2bfloat16(v.y);
      xs[c4*4+2][nl] = __float2bfloat16(v.z);
      xs[c4*4+3][nl] = __float2bfloat16(v.w);
    }
    __syncthreads();

    const int og  = tid & 7;
    const int nl0 = (tid >> 3) * 2;   // 2 nodes per thread
    float acc[2][8];
    #pragma unroll
    for (int t=0;t<2;++t){
      #pragma unroll
      for (int j=0;j<8;++j) acc[t][j]=0.f;
    }
    #pragma unroll 4
    for (int i=0;i<64;++i){
      float4 wa = *reinterpret_cast<const float4*>(&wt[i][og*8]);
      float4 wb = *reinterpret_cast<const float4*>(&wt[i][og*8+4]);
      unsigned xv = *reinterpret_cast<const unsigned*>(&xs[i][nl0]);  // 2 bf16, 4B aligned
      float x0 = __uint_as_float(xv << 16);
      float x1 = __uint_as_float(xv & 0xFFFF0000u);
      acc[0][0] += x0*wa.x; acc[0][1] += x0*wa.y; acc[0][2] += x0*wa.z; acc[0][3] += x0*wa.w;
      acc[0][4] += x0*wb.x; acc[0][5] += x0*wb.y; acc[0][6] += x0*wb.z; acc[0][7] += x0*wb.w;
      acc[1][0] += x1*wa.x; acc[1][1] += x1*wa.y; acc[1][2] += x1*wa.z; acc[1][3] += x1*wa.w;
      acc[1][4] += x1*wb.x; acc[1][5] += x1*wb.y; acc[1][6] += x1*wb.z; acc[1][7] += x1*wb.w;
    }
    float4 b0 = reinterpret_cast<const float4*>(bias)[og*2];
    float4 b1 = reinterpret_cast<const float4*>(bias)[og*2+1];
    float bb[8] = {b0.x,b0.y,b0.z,b0.w,b1.x,b1.y,b1.z,b1.w};
    #pragma unroll
    for (int t=0;t<2;++t){
      int n = nbase + nl0 + t;
      if (n < NN){
        union { uint4 u4; __hip_bfloat16 v[8]; } pk;
        #pragma unroll
        for (int j=0;j<8;++j) pk.v[j] = __float2bfloat16(acc[t][j] + bb[j]);
        reinterpret_cast<uint4*>(&hb[(size_t)n*64])[og] = pk.u4;
      }
    }
  } else {
    // ---------- bin: 4096 edge pairs/block, edges held in registers ----------
    int* hist  = reinterpret_cast<int*>(sm);
    int* bbase = hist + NB;
    int* bcur  = bbase + NB;
    for (int i = tid; i < NB; i += 256) hist[i] = 0;
    __syncthreads();
    const int e0 = sub * 4096;
    int ra[16], rc[16];
    #pragma unroll
    for (int r = 0; r < 16; ++r){
      int i = e0 + r*256 + tid;
      if (i < EE){
        ra[r] = ei[i]; rc[r] = ei[EE + i];
        atomicAdd(&hist[rc[r] >> 7], 1);
        atomicAdd(&hist[ra[r] >> 7], 1);
      } else ra[r] = -1;
    }
    __syncthreads();
    for (int bk = tid; bk < NB; bk += 256){
      int hh = hist[bk];
      bbase[bk] = hh ? atomicAdd(&bcnt[bk], hh) : 0;
      bcur[bk]  = 0;
    }
    __syncthreads();
    #pragma unroll
    for (int r = 0; r < 16; ++r){
      if (ra[r] >= 0){
        int a = ra[r], c = rc[r];
        int b1 = c >> 7, b2 = a >> 7;
        int p1 = bbase[b1] + atomicAdd(&bcur[b1], 1);
        int p2 = bbase[b2] + atomicAdd(&bcur[b2], 1);
        if (p1 < CAPB) bbuf[(size_t)b1*CAPB + p1] = ((unsigned)a << 7) | (unsigned)(c & 127);
        if (p2 < CAPB) bbuf[(size_t)b2*CAPB + p2] = ((unsigned)c << 7) | (unsigned)(a & 127);
      }
    }
  }
}

// One block per bucket: dedup in LDS hash, inject self loops, then a single
// HT scan that simultaneously compacts src lists and counts degrees.
extern "C" __global__ __launch_bounds__(256)
void k_dedup(const int* __restrict__ bcnt, const unsigned int* __restrict__ bbuf,
             unsigned int* __restrict__ srclist, int* __restrict__ cnt,
             float* __restrict__ inv){
  __shared__ unsigned int HT[HTS];   // 32KB
  __shared__ int dcur[128];
  const int tid = threadIdx.x;
  const int b   = blockIdx.x;
  const int d0  = b << 7;
  uint4* HT4 = reinterpret_cast<uint4*>(HT);
  #pragma unroll
  for (int r = 0; r < 8; ++r) HT4[r*256 + tid] = make_uint4(EMPTY,EMPTY,EMPTY,EMPTY);
  if (tid < 128) dcur[tid] = 0;
  __syncthreads();

  int n = bcnt[b]; if (n > CAPB) n = CAPB;
  const unsigned int* buf = bbuf + (size_t)b * CAPB;
  for (int k = tid; k < n; k += 256){
    unsigned int pk  = buf[k];
    unsigned int idx = mix32(pk) & (HTS-1);
    for (;;){
      unsigned int prev = atomicCAS(&HT[idx], EMPTY, pk);
      if (prev == EMPTY || prev == pk) break;
      idx = (idx + 1) & (HTS-1);
    }
  }
  if (tid < 128 && d0 + tid < NN){      // self loop (src=dst=d0+tid)
    unsigned int pk  = ((unsigned)(d0 + tid) << 7) | (unsigned)tid;
    unsigned int idx = mix32(pk) & (HTS-1);
    for (;;){
      unsigned int prev = atomicCAS(&HT[idx], EMPTY, pk);
      if (prev == EMPTY || prev == pk) break;
      idx = (idx + 1) & (HTS-1);
    }
  }
  __syncthreads();

  // single scan: compact + count
  for (int i = tid; i < HTS; i += 256){
    unsigned int v = HT[i];
    if (v != EMPTY){
      int dl  = v & 127;
      int pos = atomicAdd(&dcur[dl], 1);
      if (pos < CAP) srclist[(size_t)(d0 + dl) * CAP + pos] = v >> 7;
    }
  }
  __syncthreads();
  if (tid < 128 && d0 + tid < NN){
    int c = dcur[tid];
    cnt[d0 + tid] = c;
    inv[d0 + tid] = rsqrtf((float)c);
  }
}

// One wave per dst. lane = dim-PAIR (u32 = 2 bf16); half-wave 0 processes
// even edges, half-wave 1 odd edges; 8 pair-accumulators (8 gathers in
// flight per wave); __shfl_xor(32) combine; float2 coalesced store.
extern "C" __global__ __launch_bounds__(256)
void k_agg(const __hip_bfloat16* __restrict__ hb, const float* __restrict__ inv,
           const int* __restrict__ cnt, const unsigned int* __restrict__ srclist,
           float* __restrict__ out){
  __shared__ uint2 sv[4][CAP];   // .x = src, .y = f32 bits of inv[src]
  const int wv   = threadIdx.x >> 6;
  const int lane = threadIdx.x & 63;
  const int half = lane >> 5;
  const int pl   = lane & 31;
  const int d    = blockIdx.x*4 + wv;
  if (d >= NN) return;
  const unsigned int* reg = srclist + (size_t)d * CAP;
  int c = cnt[d]; if (c > CAP) c = CAP;
  const int c16 = (c + 15) & ~15;

  if (lane < c){
    unsigned s = reg[lane];
    sv[wv][lane] = make_uint2(s, __float_as_uint(inv[s]));
  }
  if (64 + lane < c){
    unsigned s = reg[64 + lane];
    sv[wv][64 + lane] = make_uint2(s, __float_as_uint(inv[s]));
  }
  { int p = c + lane; if (p < c16) sv[wv][p] = make_uint2(0u, 0u); }

  const char* hbase = (const char*)hb;
  const int   boff  = pl << 2;    // byte offset of this dim pair within a row
  float ax[8], ay[8];
  #pragma unroll
  for (int u=0;u<8;++u){ ax[u]=0.f; ay[u]=0.f; }
  #pragma unroll 1
  for (int j = 0; j < c16; j += 16){
    #pragma unroll
    for (int u = 0; u < 8; ++u){
      uint2 e = sv[wv][j + 2*u + half];
      float w = __uint_as_float(e.y);
      unsigned hv = *reinterpret_cast<const unsigned*>(hbase + ((size_t)e.x << 7) + boff);
      ax[u] += w * __uint_as_float(hv << 16);
      ay[u] += w * __uint_as_float(hv & 0xFFFF0000u);
    }
  }
  float rx = ((ax[0]+ax[1])+(ax[2]+ax[3])) + ((ax[4]+ax[5])+(ax[6]+ax[7]));
  float ry = ((ay[0]+ay[1])+(ay[2]+ay[3])) + ((ay[4]+ay[5])+(ay[6]+ay[7]));
  rx += __shfl_xor(rx, 32);
  ry += __shfl_xor(ry, 32);
  if (half == 0){
    float iv = inv[d];
    float2 o = make_float2(rx * iv, ry * iv);
    *reinterpret_cast<float2*>(&out[(size_t)d*64 + (pl << 1)]) = o;
  }
}

extern "C" void kernel_launch(void* const* d_in, const int* in_sizes, int n_in,
                              void* d_out, int out_size, void* d_ws, size_t ws_size,
                              hipStream_t stream){
  (void)in_sizes; (void)n_in; (void)out_size; (void)ws_size;
  const float* x  = (const float*)d_in[0];
  const int*   ei = (const int*)  d_in[1];
  const float* W  = (const float*)d_in[2];
  const float* b  = (const float*)d_in[3];
  float* out = (float*)d_out;

  char* ws = (char*)d_ws;
  __hip_bfloat16* hb      = (__hip_bfloat16*)ws;            // 12.8 MB
  float*          inv     = (float*)(ws + 12800000);        // 0.4 MB
  int*            cnt     = (int*)  (ws + 13200000);        // 0.4 MB
  unsigned int*   srclist = (unsigned int*)(ws + 13600000); // 51.2 MB
  int*            bcnt    = (int*)  (ws + 64800000);        // 4 KB
  unsigned int*   bbuf    = (unsigned int*)(ws + 64804096); // 16.0 MB (end ~80.8 MB)

  hipMemsetAsync(bcnt, 0, NB * 4, stream);

  k_prep  <<<GLIN + GBIN, 256, 0, stream>>>(x, W, b, hb, ei, bcnt, bbuf);
  k_dedup <<<NB, 256, 0, stream>>>(bcnt, bbuf, srclist, cnt, inv);
  k_agg   <<<(NN + 3)/4, 256, 0, stream>>>(hb, inv, cnt, srclist, out);
}